// Round 1
// 160.286 us; speedup vs baseline: 1.3047x; 1.3047x over previous
//
#include <hip/hip_runtime.h>

#define N_NODES 50000
#define DIM 256
#define NEG 0.2f
#define LN_EPS 1e-5f
#define SCAT_BLOCKS 2048

typedef __attribute__((ext_vector_type(8))) short short8;   // 8 x bf16 (4 VGPRs)
typedef __attribute__((ext_vector_type(4))) float f32x4;    // MFMA accumulator

__device__ __forceinline__ unsigned short f2bf(float x) {   // RNE fp32 -> bf16
    unsigned int u = __builtin_bit_cast(unsigned int, x);
    u += 0x7fffu + ((u >> 16) & 1u);
    return (unsigned short)(u >> 16);
}

__device__ __forceinline__ void load_lds16(const void* g, void* l) {
    // async global->LDS, 16B/lane, dest = wave-uniform base + lane*16 (linear)
    __builtin_amdgcn_global_load_lds((const unsigned int*)g, (unsigned int*)l, 16, 0, 0);
}

// ---------- prep: Wr -> fragment-ordered bf16 WrF  +  relation byte-mask scatter ----------
// WrF layout: frag f = mt*8+kk (mt = 16-col m-tile, kk = 32-wide k-step), 64 lanes x 16B:
//   WrF[(f*64+lane)*8 + j] = bf16(Wr[kk*32 + (lane>>4)*8 + j][mt*16 + (lane&15)])
// i.e. exactly the per-lane MFMA A-fragment, 16B contiguous per lane -> global_load_lds
// stages it linearly and ds_read_b128 at lane*16 is bank-conflict-free.
__global__ __launch_bounds__(256) void prep(
    const float* __restrict__ Wr, unsigned short* __restrict__ WrF,
    const int* __restrict__ d0, const int* __restrict__ d1, const int* __restrict__ d2,
    int E, unsigned char* __restrict__ mask)
{
    if (blockIdx.x < 32) {                       // 32*256 = 8192 = 128 frags x 64 lanes
        const int o    = blockIdx.x * 256 + threadIdx.x;
        const int lane = o & 63;
        const int frag = o >> 6;                 // mt*8 + kk
        const int kk = frag & 7, mt = frag >> 3;
        const int ln = lane & 15, quad = lane >> 4;
        const float* src = Wr + (size_t)(kk * 32 + quad * 8) * DIM + mt * 16 + ln;
        short8 v;
        #pragma unroll
        for (int j = 0; j < 8; ++j) v[j] = (short)f2bf(src[(size_t)j * DIM]);
        *(short8*)(WrF + (size_t)o * 8) = v;
    } else {
        // racing byte-stores of the same value are benign; memset zeroed the mask
        const int total = 3 * E;
        for (int i = (blockIdx.x - 32) * 256 + (int)threadIdx.x; i < total;
             i += SCAT_BLOCKS * 256) {
            const int* d; int base, e;
            if (i >= 2 * E)  { d = d2; e = i - 2 * E; base = 2 * N_NODES; }
            else if (i >= E) { d = d1; e = i - E;     base = N_NODES; }
            else             { d = d0; e = i;         base = 0; }
            mask[base + d[e]] = (unsigned char)1;
        }
    }
}

// ---------- fused MFMA GEMM + analytic-collapse epilogue ----------
// Block = 4 waves x 16 nodes = 64 nodes, all 256 out-cols, K=256.
// feat row fully prefetched to regs (16 loads, HBM latency hidden up front),
// converted to bf16 B-fragments once. WrF staged to LDS in two 64 KB phases
// (2 blocks/CU); A-fragments come from conflict-free ds_read_b128.
__global__ __launch_bounds__(256, 2) void fused_mfma(
    const float* __restrict__ feat, const unsigned short* __restrict__ WrF,
    const float* __restrict__ br, const float* __restrict__ rel_q,
    const float* __restrict__ rel_k, const float* __restrict__ gamma,
    const float* __restrict__ beta_p, const unsigned char* __restrict__ mask,
    float* __restrict__ out)
{
    __shared__ unsigned short lds[32768];        // 64 KB = one 8-m-tile phase of WrF
    const int lane = threadIdx.x & 63;
    const int wave = threadIdx.x >> 6;
    const int ln = lane & 15;      // node within wave / MFMA n
    const int quad = lane >> 4;    // MFMA k-quad & D-row-quad
    int node = blockIdx.x * 64 + wave * 16 + ln;
    const bool valid = node < N_NODES;
    if (!valid) node = N_NODES - 1;              // clamp: loads safe, store guarded

    // ---- stage phase 0 (issued first: L2 latency overlaps feat issue) ----
    {
        const char* g = (const char*)WrF;
        #pragma unroll
        for (int r = 0; r < 16; ++r) {
            const int off = wave * 16384 + r * 1024;       // wave-uniform LDS base
            load_lds16(g + off + lane * 16, (char*)lds + off);
        }
    }

    // ---- full feat-row prefetch (16 x 16B per lane) ----
    const float* fptr = feat + (size_t)node * DIM + quad * 8;
    float4 F0[8], F1[8];
    #pragma unroll
    for (int kk = 0; kk < 8; ++kk) {
        F0[kk] = *(const float4*)(fptr + kk * 32);
        F1[kk] = *(const float4*)(fptr + kk * 32 + 4);
    }
    // convert once: B-fragments for all 8 k-steps (out of the MFMA dep chain)
    short8 bfr[8];
    #pragma unroll
    for (int kk = 0; kk < 8; ++kk) {
        bfr[kk][0] = (short)f2bf(F0[kk].x); bfr[kk][1] = (short)f2bf(F0[kk].y);
        bfr[kk][2] = (short)f2bf(F0[kk].z); bfr[kk][3] = (short)f2bf(F0[kk].w);
        bfr[kk][4] = (short)f2bf(F1[kk].x); bfr[kk][5] = (short)f2bf(F1[kk].y);
        bfr[kk][6] = (short)f2bf(F1[kk].z); bfr[kk][7] = (short)f2bf(F1[kk].w);
    }

    f32x4 acc[16];
    #pragma unroll
    for (int mt = 0; mt < 16; ++mt) acc[mt] = (f32x4){0.f, 0.f, 0.f, 0.f};

    __syncthreads();                             // drains vmcnt: phase-0 staged

    #pragma unroll
    for (int kk = 0; kk < 8; ++kk) {
        #pragma unroll
        for (int mt = 0; mt < 8; ++mt) {
            const short8 a = *(const short8*)((const char*)lds
                               + (mt * 8 + kk) * 1024 + lane * 16);
            acc[mt] = __builtin_amdgcn_mfma_f32_16x16x32_bf16(a, bfr[kk], acc[mt], 0, 0, 0);
        }
    }

    __syncthreads();                             // all waves done reading phase 0

    {
        const char* g = (const char*)WrF + 65536;
        #pragma unroll
        for (int r = 0; r < 16; ++r) {
            const int off = wave * 16384 + r * 1024;
            load_lds16(g + off + lane * 16, (char*)lds + off);
        }
    }
    __syncthreads();                             // phase-1 staged

    #pragma unroll
    for (int kk = 0; kk < 8; ++kk) {
        #pragma unroll
        for (int mt = 0; mt < 8; ++mt) {
            const short8 a = *(const short8*)((const char*)lds
                               + (mt * 8 + kk) * 1024 + lane * 16);
            acc[8 + mt] = __builtin_amdgcn_mfma_f32_16x16x32_bf16(a, bfr[kk], acc[8 + mt], 0, 0, 0);
        }
    }

    // ---- epilogue: bias, per-head dots, softmax weight, ReLU, LayerNorm (proven) ----
    float qp[4] = {0.f, 0.f, 0.f, 0.f}, kp[4] = {0.f, 0.f, 0.f, 0.f};
    #pragma unroll
    for (int mt = 0; mt < 16; ++mt) {
        const int cbase = mt * 16 + quad * 4;
        const float4 bb = *(const float4*)(br + cbase);
        acc[mt][0] += bb.x; acc[mt][1] += bb.y; acc[mt][2] += bb.z; acc[mt][3] += bb.w;
        const float4 rq = *(const float4*)(rel_q + cbase);
        const float4 rk = *(const float4*)(rel_k + cbase);
        const int h = mt >> 2;
        qp[h] += acc[mt][0] * rq.x + acc[mt][1] * rq.y + acc[mt][2] * rq.z + acc[mt][3] * rq.w;
        kp[h] += acc[mt][0] * rk.x + acc[mt][1] * rk.y + acc[mt][2] * rk.z + acc[mt][3] * rk.w;
    }
    #pragma unroll
    for (int h = 0; h < 4; ++h) {
        qp[h] += __shfl_xor(qp[h], 16); qp[h] += __shfl_xor(qp[h], 32);
        kp[h] += __shfl_xor(kp[h], 16); kp[h] += __shfl_xor(kp[h], 32);
    }

    const int cnt = (int)mask[node] + (int)mask[N_NODES + node] + (int)mask[2 * N_NODES + node];

    float wgt[4];
    #pragma unroll
    for (int h = 0; h < 4; ++h) {
        const float q = qp[h];
        const float qk = q + kp[h];
        const float a = q  > 0.f ? q  : NEG * q;    // inactive-relation logit
        const float b = qk > 0.f ? qk : NEG * qk;   // active/self logit
        const float mx = fmaxf(a, b);
        const float eb = (float)(cnt + 1) * __expf(b - mx);
        const float ea = (float)(3 - cnt) * __expf(a - mx);
        wgt[h] = eb / (eb + ea);
    }

    float sum = 0.f, ssq = 0.f;
    #pragma unroll
    for (int mt = 0; mt < 16; ++mt) {
        const float w = wgt[mt >> 2];
        #pragma unroll
        for (int r = 0; r < 4; ++r) {
            float v = fmaxf(acc[mt][r] * w, 0.f);   // ReLU
            acc[mt][r] = v;
            sum += v; ssq += v * v;
        }
    }
    sum += __shfl_xor(sum, 16); sum += __shfl_xor(sum, 32);
    ssq += __shfl_xor(ssq, 16); ssq += __shfl_xor(ssq, 32);
    const float mu = sum * (1.f / 256.f);
    const float var = ssq * (1.f / 256.f) - mu * mu;
    const float rstd = rsqrtf(var + LN_EPS);

    if (valid) {
        float* optr = out + (size_t)node * DIM;
        #pragma unroll
        for (int mt = 0; mt < 16; ++mt) {
            const int cbase = mt * 16 + quad * 4;
            const float4 g = *(const float4*)(gamma + cbase);
            const float4 b = *(const float4*)(beta_p + cbase);
            float4 r;
            r.x = (acc[mt][0] - mu) * rstd * g.x + b.x;
            r.y = (acc[mt][1] - mu) * rstd * g.y + b.y;
            r.z = (acc[mt][2] - mu) * rstd * g.z + b.z;
            r.w = (acc[mt][3] - mu) * rstd * g.w + b.w;
            *(float4*)(optr + cbase) = r;
        }
    }
}

extern "C" void kernel_launch(void* const* d_in, const int* in_sizes, int n_in,
                              void* d_out, int out_size, void* d_ws, size_t ws_size,
                              hipStream_t stream) {
    const float* feat  = (const float*)d_in[0];
    // d_in[1] Wl, d_in[2] bl, d_in[5] attn_l, d_in[6] attn_r, edge_src_*: dead code
    const float* Wr    = (const float*)d_in[3];
    const float* br    = (const float*)d_in[4];
    const float* rel_q = (const float*)d_in[7];
    const float* rel_k = (const float*)d_in[8];
    const float* gamma = (const float*)d_in[9];
    const float* beta  = (const float*)d_in[10];
    const int* dst0 = (const int*)d_in[12];
    const int* dst1 = (const int*)d_in[14];
    const int* dst2 = (const int*)d_in[16];
    const int E = in_sizes[12];

    // d_ws layout: WrF fragment-ordered bf16 (131072 B) | byte mask (150016 B)
    unsigned short* WrF = (unsigned short*)d_ws;
    unsigned char* mask = (unsigned char*)d_ws + DIM * DIM * 2;

    hipMemsetAsync(mask, 0, 150016, stream);
    prep<<<32 + SCAT_BLOCKS, 256, 0, stream>>>(Wr, WrF, dst0, dst1, dst2, E, mask);
    fused_mfma<<<(N_NODES + 63) / 64, 256, 0, stream>>>(
        feat, WrF, br, rel_q, rel_k, gamma, beta, mask, (float*)d_out);
}